// Round 15
// baseline (41.635 us; speedup 1.0000x reference)
//
#include <hip/hip_runtime.h>
#include <math.h>

namespace {

constexpr int N  = 4096;
constexpr int E  = 256;
constexpr int H  = 8;
constexpr int DH = 32;
constexpr int BS = 8;
// fold 1/sqrt(DH) and log2(e): softmax in exp2 domain, no max subtraction
// (f32-safe: |s*CL| realistic max ~16, overflow at 127 -> 27 sigma margin)
constexpr float CL = 0.17677669529663687f * 1.4426950408889634f;

typedef __bf16 bf16x8 __attribute__((ext_vector_type(8)));
typedef __bf16 bf16x4 __attribute__((ext_vector_type(4)));
typedef float  f32x4  __attribute__((ext_vector_type(4)));

#if __has_builtin(__builtin_amdgcn_exp2f)
#define EXP2F(x) __builtin_amdgcn_exp2f(x)
#else
#define EXP2F(x) __expf((x) * 0.6931471805599453f)
#endif

__device__ inline bf16x8 pack8(float4 a, float4 b) {
  bf16x8 r;
  r[0] = (__bf16)a.x; r[1] = (__bf16)a.y; r[2] = (__bf16)a.z; r[3] = (__bf16)a.w;
  r[4] = (__bf16)b.x; r[5] = (__bf16)b.y; r[6] = (__bf16)b.z; r[7] = (__bf16)b.w;
  return r;
}

// ===========================================================================
// FRAGMENT-MAJOR LAYOUTS (proven round 12: 68.7 -> 38.5 us):
// every MFMA operand lives in memory as [frag][lane(64)][elem(8)] so the
// consuming wave loads it as ONE coalesced 1KB instruction (16B/lane).
//   xpe/xv : frag_id = rowtile(256)*8 + ktile(8)
//   wfrag  : per mat, frag_id = n16(16)*8 + ktile
//   qfrag  : frag_id = head*256 + rowtile
//   kfrag  : frag_id = (head*64 + keytile64)*4 + mt  (key-ID perm baked in)
//   vfrag  : frag_id = ((head*64+keytile64)*2+ks)*2+dh
// ===========================================================================

// ---------------------------------------------------------------------------
// prep: fragment-major bf16 conversion of x+pe, x, and the 4 weight mats.
// (frozen from round 12)
// ---------------------------------------------------------------------------
__global__ __launch_bounds__(256) void prep_kernel(
    const float* __restrict__ x, const float* __restrict__ pe,
    const int* __restrict__ xb,
    const float* __restrict__ Wq, const float* __restrict__ Wk,
    const float* __restrict__ Wv, const float* __restrict__ Wo,
    __bf16* __restrict__ xpef, __bf16* __restrict__ xvf,
    __bf16* __restrict__ wfrag, int* __restrict__ seg)
{
  const int bid  = blockIdx.x;
  const int wv4  = threadIdx.x >> 6;
  const int lane = threadIdx.x & 63;
  const int l15  = lane & 15, g = lane >> 4;

  if (bid < 512) {
    const int wid = bid * 4 + wv4;            // = rt*8 + kt
    const int rt = wid >> 3, kt = wid & 7;
    const float* xr = x  + (size_t)(rt * 16 + l15) * E + kt * 32 + 8 * g;
    const float* pr = pe + (size_t)(rt * 16 + l15) * E + kt * 32 + 8 * g;
    float4 a0 = *(const float4*)xr;
    float4 a1 = *(const float4*)(xr + 4);
    const float4 p0 = *(const float4*)pr;
    const float4 p1 = *(const float4*)(pr + 4);
    *reinterpret_cast<bf16x8*>(xvf + (size_t)wid * 512 + lane * 8) = pack8(a0, a1);
    a0.x += p0.x; a0.y += p0.y; a0.z += p0.z; a0.w += p0.w;
    a1.x += p1.x; a1.y += p1.y; a1.z += p1.z; a1.w += p1.w;
    *reinterpret_cast<bf16x8*>(xpef + (size_t)wid * 512 + lane * 8) = pack8(a0, a1);
  } else if (bid < 640) {
    const int wid = (bid - 512) * 4 + wv4;    // [0,512)
    const int mat = wid >> 7;
    const int rem = wid & 127;                // n16*8 + kt
    const int n16 = rem >> 3, kt = rem & 7;
    const float* __restrict__ W =
        (mat == 0) ? Wq : (mat == 1) ? Wk : (mat == 2) ? Wv : Wo;
    const float* wr = W + (size_t)(n16 * 16 + l15) * E + kt * 32 + 8 * g;
    *reinterpret_cast<bf16x8*>(wfrag + (size_t)wid * 512 + lane * 8) =
        pack8(*(const float4*)wr, *(const float4*)(wr + 4));
  } else {
    if (threadIdx.x <= BS) {
      const int t = threadIdx.x;
      int lo = 0, hi = N;
      while (lo < hi) { int mid = (lo + hi) >> 1; if (xb[mid] < t) lo = mid + 1; else hi = mid; }
      seg[t] = lo;
    }
  }
}

// ---------------------------------------------------------------------------
// MFMA QKV from fragment-major operands, A-reuse + W-window prefetch.
// (frozen from round 14)
// ---------------------------------------------------------------------------
__global__ __launch_bounds__(256) void qkv_mfma(
    const __bf16* __restrict__ xpef, const __bf16* __restrict__ xvf,
    const __bf16* __restrict__ wfrag,
    const float* __restrict__ bq, const float* __restrict__ bk,
    const float* __restrict__ bv,
    __bf16* __restrict__ qfrag, __bf16* __restrict__ kfrag,
    __bf16* __restrict__ vfrag)
{
  const int mat  = blockIdx.y;
  const int rt   = blockIdx.x;
  const int wv   = threadIdx.x >> 6;
  const int lane = threadIdx.x & 63;
  const int l15  = lane & 15, g = lane >> 4;
  const int m0   = rt * 16;

  const __bf16* __restrict__ A = (mat < 2) ? xpef : xvf;
  const __bf16* __restrict__ W = wfrag + (size_t)mat * 65536;

  bf16x8 af[8];
#pragma unroll
  for (int kk = 0; kk < 8; ++kk)
    af[kk] = *reinterpret_cast<const bf16x8*>(A + (size_t)(rt * 8 + kk) * 512 + lane * 8);

  const int token = m0 + l15;

#pragma unroll
  for (int p = 0; p < 2; ++p) {
    const int cb0  = wv * 64 + p * 32;
    const int n16b = cb0 >> 4;
    const __bf16* __restrict__ Wp0 = W + (size_t)(n16b * 8) * 512 + lane * 8;
    const __bf16* __restrict__ Wp1 = W + (size_t)((n16b + 1) * 8) * 512 + lane * 8;

    f32x4 acc0 = {0.f, 0.f, 0.f, 0.f};
    f32x4 acc1 = {0.f, 0.f, 0.f, 0.f};

    bf16x8 ww[4];
    ww[0] = *reinterpret_cast<const bf16x8*>(Wp0);
    ww[1] = *reinterpret_cast<const bf16x8*>(Wp1);
    ww[2] = *reinterpret_cast<const bf16x8*>(Wp0 + 512);
    ww[3] = *reinterpret_cast<const bf16x8*>(Wp1 + 512);

#pragma unroll
    for (int kk = 0; kk < 8; ++kk) {
      const bf16x8 cw0 = ww[(2 * kk) & 3];
      const bf16x8 cw1 = ww[(2 * kk + 1) & 3];
      if (kk < 6) {
        ww[(2 * kk) & 3]     = *reinterpret_cast<const bf16x8*>(Wp0 + (size_t)(kk + 2) * 512);
        ww[(2 * kk + 1) & 3] = *reinterpret_cast<const bf16x8*>(Wp1 + (size_t)(kk + 2) * 512);
      }
      acc0 = __builtin_amdgcn_mfma_f32_16x16x32_bf16(cw0, af[kk], acc0, 0, 0, 0);
      acc1 = __builtin_amdgcn_mfma_f32_16x16x32_bf16(cw1, af[kk], acc1, 0, 0, 0);
    }

    const f32x4 accs[2] = {acc0, acc1};
    if (mat < 2) {
      const float* __restrict__ bi = mat ? bk : bq;
      __bf16* __restrict__ dst = mat ? kfrag : qfrag;
#pragma unroll
      for (int nt = 0; nt < 2; ++nt) {
        const int e  = cb0 + nt * 16 + 4 * g;   // 4 consecutive dims r=0..3
        const float4 bb = *(const float4*)(bi + e);
        const int h  = e >> 5;
        const int gp = (e & 31) >> 3;
        const int ib = e & 7;                   // 4*(g&1)
        bf16x4 o;
        o.x = (__bf16)(accs[nt][0] + bb.x);
        o.y = (__bf16)(accs[nt][1] + bb.y);
        o.z = (__bf16)(accs[nt][2] + bb.z);
        o.w = (__bf16)(accs[nt][3] + bb.w);
        size_t idx;
        if (mat == 0) {
          const int lp = (token & 15) + 16 * gp;
          idx = ((size_t)(h * 256 + rt) * 64 + lp) * 8 + ib;
        } else {
          const int t  = token >> 6, tk = token & 63;
          const int mt = 2 * (tk >> 5) + ((tk >> 2) & 1);
          const int lp = 4 * ((tk >> 3) & 3) + (tk & 3) + 16 * gp;
          idx = ((size_t)((h * 64 + t) * 4 + mt) * 64 + lp) * 8 + ib;
        }
        *reinterpret_cast<bf16x4*>(dst + idx) = o;
      }
    } else {
      const int t  = token >> 6, tk = token & 63;
      const int ks = (tk >> 5) & 1;
      const int gp = (tk >> 3) & 3;
      const int i  = tk & 7;
#pragma unroll
      for (int nt = 0; nt < 2; ++nt) {
        const int e0 = cb0 + nt * 16 + 4 * g;
        const float4 bb = *(const float4*)(bv + e0);
        const float bbr[4] = {bb.x, bb.y, bb.z, bb.w};
#pragma unroll
        for (int r = 0; r < 4; ++r) {
          const int d  = e0 + r;
          const int h  = d >> 5, dh = (d >> 4) & 1;
          const size_t idx =
              ((size_t)(((h * 64 + t) * 2 + ks) * 2 + dh) * 64 + (d & 15) + 16 * gp) * 8 + i;
          vfrag[idx] = (__bf16)(accs[nt][r] + bbr[r]);
        }
      }
    }
  }
}

// ---------------------------------------------------------------------------
// Fused attention + projection + residual + LayerNorm, fragment-major,
// KEY-SPLIT x2 (revisit of r8 in the post-r12 latency-bound regime).
// Block = 16 query rows, 1024 threads = 16 waves: wave = (split s, head h).
// Each (h,s) wave runs the EXACT r12 loop body on tiles t0+s, t0+s+2, ...
// (fixed-base exp2 softmax is associative over keys), depositing
// UNNORMALIZED bf16 partial ctx + partial row-sums in LDS. Phase B:
// 16 waves x 16-col slices combine the two splits, normalize per
// (row, head=col/32=kk), then proj + residual + LN.
// 16 waves/CU (4/SIMD) vs r12's 8 — doubles latency-hiding TLP.
// ---------------------------------------------------------------------------
__global__ __launch_bounds__(1024) void attn_proj_ln(
    const __bf16* __restrict__ qfrag, const __bf16* __restrict__ kfrag,
    const __bf16* __restrict__ vfrag, const int* __restrict__ xb,
    const int* __restrict__ seg,
    const float* __restrict__ x, const __bf16* __restrict__ wofrag,
    const float* __restrict__ bo, const float* __restrict__ gamma,
    const float* __restrict__ beta, float* __restrict__ out)
{
  const int rt   = blockIdx.x;
  const int m0   = rt * 16;
  const int wv   = threadIdx.x >> 6;    // [0,16)
  const int h    = wv & 7;              // head
  const int s    = wv >> 3;             // key-split half
  const int lane = threadIdx.x & 63;
  const int l15  = lane & 15;
  const int g    = lane >> 4;
  const int qrow = m0 + l15;

  __shared__ __bf16 cl[2][16][264];     // unnormalized partial ctx per split
  __shared__ float  lsW[2][8][16];      // partial row-sums per (split, head)
  __shared__ float  redS[16][16];
  __shared__ float  redQ[16][16];

  // hoist this wave's phase-B Wo fragments (n16 = wv)
  bf16x8 wreg[8];
#pragma unroll
  for (int kk = 0; kk < 8; ++kk)
    wreg[kk] = *reinterpret_cast<const bf16x8*>(
        wofrag + (size_t)(wv * 8 + kk) * 512 + lane * 8);

  // ======== phase A: attention (r12 body, tiles t0+s, t0+s+2, ...) ========
  {
    const int b  = xb[qrow];
    const int lo = seg[b];
    const int hi = seg[b + 1];

    const bf16x8 qf = *reinterpret_cast<const bf16x8*>(
        qfrag + (size_t)(h * 256 + rt) * 512 + lane * 8);

    const int kstart = __shfl(lo, 0, 64);
    const int kend   = __shfl(hi, 15, 64);
    const int t0     = kstart >> 6;

    f32x4 acc0 = {0.f, 0.f, 0.f, 0.f};
    f32x4 acc1 = {0.f, 0.f, 0.f, 0.f};
    float lsum = 0.f;

    for (int t = t0 + s; t * 64 < kend; t += 2) {
      const int j0 = t * 64;
      const __bf16* kb4 = kfrag + (size_t)(h * 64 + t) * 2048 + lane * 8;
      const __bf16* vb4 = vfrag + (size_t)(h * 64 + t) * 2048 + lane * 8;

      const bf16x8 kf0 = *reinterpret_cast<const bf16x8*>(kb4);
      const bf16x8 kf1 = *reinterpret_cast<const bf16x8*>(kb4 + 512);
      const bf16x8 kf2 = *reinterpret_cast<const bf16x8*>(kb4 + 1024);
      const bf16x8 kf3 = *reinterpret_cast<const bf16x8*>(kb4 + 1536);
      const bf16x8 vf00 = *reinterpret_cast<const bf16x8*>(vb4);          // ks0,dh0
      const bf16x8 vf01 = *reinterpret_cast<const bf16x8*>(vb4 + 512);    // ks0,dh1
      const bf16x8 vf10 = *reinterpret_cast<const bf16x8*>(vb4 + 1024);   // ks1,dh0
      const bf16x8 vf11 = *reinterpret_cast<const bf16x8*>(vb4 + 1536);   // ks1,dh1

      const f32x4 z = {0.f, 0.f, 0.f, 0.f};
      f32x4 sc4[4];
      sc4[0] = __builtin_amdgcn_mfma_f32_16x16x32_bf16(kf0, qf, z, 0, 0, 0);
      sc4[1] = __builtin_amdgcn_mfma_f32_16x16x32_bf16(kf1, qf, z, 0, 0, 0);
      sc4[2] = __builtin_amdgcn_mfma_f32_16x16x32_bf16(kf2, qf, z, 0, 0, 0);
      sc4[3] = __builtin_amdgcn_mfma_f32_16x16x32_bf16(kf3, qf, z, 0, 0, 0);

      bf16x8 pa[2];
#pragma unroll
      for (int ks = 0; ks < 2; ++ks)
#pragma unroll
        for (int b_ = 0; b_ < 2; ++b_)
#pragma unroll
          for (int r = 0; r < 4; ++r) {
            const int key = j0 + 32 * ks + 8 * g + 4 * b_ + r;
            const float sc = sc4[2 * ks + b_][r] * CL;
            const float e  = (key >= lo && key < hi) ? EXP2F(sc) : 0.f;
            lsum += e;
            pa[ks][4 * b_ + r] = (__bf16)e;
          }

      acc0 = __builtin_amdgcn_mfma_f32_16x16x32_bf16(pa[0], vf00, acc0, 0, 0, 0);
      acc1 = __builtin_amdgcn_mfma_f32_16x16x32_bf16(pa[0], vf01, acc1, 0, 0, 0);
      acc0 = __builtin_amdgcn_mfma_f32_16x16x32_bf16(pa[1], vf10, acc0, 0, 0, 0);
      acc1 = __builtin_amdgcn_mfma_f32_16x16x32_bf16(pa[1], vf11, acc1, 0, 0, 0);
    }

    // partial row-sums (rows l15, this head, this split)
    lsum += __shfl_xor(lsum, 16, 64);
    lsum += __shfl_xor(lsum, 32, 64);
    if (lane < 16) lsW[s][h][lane] = lsum;

    // unnormalized partial ctx -> LDS (bf16)
#pragma unroll
    for (int r = 0; r < 4; ++r) {
      cl[s][4 * g + r][h * DH + l15]      = (__bf16)(acc0[r]);
      cl[s][4 * g + r][h * DH + 16 + l15] = (__bf16)(acc1[r]);
    }
  }
  __syncthreads();

  // ======== phase B: combine + normalize + proj + residual + LN ========
  {
    // A-fragments: combine splits, normalize per (row=l15, head=kk)
    bf16x8 af[8];
#pragma unroll
    for (int kk = 0; kk < 8; ++kk) {
      const int cc = kk * 32 + 8 * g;
      const bf16x8 a0 = *reinterpret_cast<const bf16x8*>(&cl[0][l15][cc]);
      const bf16x8 a1 = *reinterpret_cast<const bf16x8*>(&cl[1][l15][cc]);
      const float inv = 1.0f / (lsW[0][kk][l15] + lsW[1][kk][l15]);
#pragma unroll
      for (int i = 0; i < 8; ++i)
        af[kk][i] = (__bf16)(((float)a0[i] + (float)a1[i]) * inv);
    }

    f32x4 acc = {0.f, 0.f, 0.f, 0.f};
#pragma unroll
    for (int kk = 0; kk < 8; ++kk)
      acc = __builtin_amdgcn_mfma_f32_16x16x32_bf16(af[kk], wreg[kk], acc, 0, 0, 0);

    // y[m0+4g+r][wv*16+l15] = acc[r] + bo + x ; LN stats
    const int c = wv * 16 + l15;
    const float bb = bo[c];
    float yv[4], s1[4], s2[4];
#pragma unroll
    for (int r = 0; r < 4; ++r) {
      const int row = m0 + 4 * g + r;
      const float y = acc[r] + bb + x[(size_t)row * E + c];
      yv[r] = y;
      s1[r] = y;
      s2[r] = y * y;
    }
#pragma unroll
    for (int off = 1; off < 16; off <<= 1) {
#pragma unroll
      for (int r = 0; r < 4; ++r) {
        s1[r] += __shfl_xor(s1[r], off, 64);
        s2[r] += __shfl_xor(s2[r], off, 64);
      }
    }
    if (l15 == 0) {
#pragma unroll
      for (int r = 0; r < 4; ++r) {
        redS[wv][4 * g + r] = s1[r];
        redQ[wv][4 * g + r] = s2[r];
      }
    }
    __syncthreads();
    float mu[4], rs[4];
#pragma unroll
    for (int r = 0; r < 4; ++r) {
      float ts = 0.f, tq = 0.f;
#pragma unroll
      for (int w = 0; w < 16; ++w) {
        ts += redS[w][4 * g + r];
        tq += redQ[w][4 * g + r];
      }
      mu[r] = ts * (1.0f / E);
      const float var = tq * (1.0f / E) - mu[r] * mu[r];
      rs[r] = rsqrtf(var + 1e-5f);
    }
    const float gg = gamma[c];
    const float bt = beta[c];
#pragma unroll
    for (int r = 0; r < 4; ++r) {
      const int row = m0 + 4 * g + r;
      out[(size_t)row * E + c] = (yv[r] - mu[r]) * rs[r] * gg + bt;
    }
  }
}

}  // namespace

extern "C" void kernel_launch(void* const* d_in, const int* in_sizes, int n_in,
                              void* d_out, int out_size, void* d_ws, size_t ws_size,
                              hipStream_t stream) {
  const float* x     = (const float*)d_in[0];
  const float* pe    = (const float*)d_in[1];
  const int*   xb    = (const int*)d_in[2];
  const float* Wq    = (const float*)d_in[3];
  const float* Wk    = (const float*)d_in[4];
  const float* Wv    = (const float*)d_in[5];
  const float* bq    = (const float*)d_in[6];
  const float* bk    = (const float*)d_in[7];
  const float* bv    = (const float*)d_in[8];
  const float* Wo    = (const float*)d_in[9];
  const float* bo    = (const float*)d_in[10];
  const float* gamma = (const float*)d_in[11];
  const float* beta  = (const float*)d_in[12];
  float* out = (float*)d_out;

  __bf16* ws = (__bf16*)d_ws;
  const size_t NE = (size_t)N * E;          // 1,048,576 elements
  __bf16* qfrag = ws;                       // 2 MB
  __bf16* kfrag = ws + NE;                  // 2 MB
  __bf16* vfrag = ws + 2 * NE;              // 2 MB
  __bf16* xpef  = ws + 3 * NE;              // 2 MB
  __bf16* xvf   = ws + 4 * NE;              // 2 MB
  __bf16* wfrag = ws + 5 * NE;              // 512 KB (4 mats x 65536)
  int*    seg   = (int*)(ws + 5 * NE + 4 * 65536);

  prep_kernel<<<dim3(641), 256, 0, stream>>>(x, pe, xb, Wq, Wk, Wv, Wo,
                                             xpef, xvf, wfrag, seg);
  qkv_mfma<<<dim3(256, 3), 256, 0, stream>>>(xpef, xvf, wfrag, bq, bk, bv,
                                             qfrag, kfrag, vfrag);
  attn_proj_ln<<<dim3(256), 1024, 0, stream>>>(qfrag, kfrag, vfrag, xb, seg,
                                               x, wfrag + 3 * 65536,
                                               bo, gamma, beta, out);
}

// Round 16
// 40.543 us; speedup vs baseline: 1.0269x; 1.0269x over previous
//
#include <hip/hip_runtime.h>
#include <math.h>

namespace {

constexpr int N  = 4096;
constexpr int E  = 256;
constexpr int H  = 8;
constexpr int DH = 32;
constexpr int BS = 8;
// fold 1/sqrt(DH) and log2(e): softmax in exp2 domain, no max subtraction
// (f32-safe: |s*CL| realistic max ~16, overflow at 127 -> 27 sigma margin)
// NEW (r16): CL is folded into qfrag at the qkv epilogue.
constexpr float CL = 0.17677669529663687f * 1.4426950408889634f;

typedef __bf16 bf16x8 __attribute__((ext_vector_type(8)));
typedef __bf16 bf16x4 __attribute__((ext_vector_type(4)));
typedef float  f32x4  __attribute__((ext_vector_type(4)));

#if __has_builtin(__builtin_amdgcn_exp2f)
#define EXP2F(x) __builtin_amdgcn_exp2f(x)
#else
#define EXP2F(x) __expf((x) * 0.6931471805599453f)
#endif

__device__ inline bf16x8 pack8(float4 a, float4 b) {
  bf16x8 r;
  r[0] = (__bf16)a.x; r[1] = (__bf16)a.y; r[2] = (__bf16)a.z; r[3] = (__bf16)a.w;
  r[4] = (__bf16)b.x; r[5] = (__bf16)b.y; r[6] = (__bf16)b.z; r[7] = (__bf16)b.w;
  return r;
}

// ===========================================================================
// FRAGMENT-MAJOR LAYOUTS (proven round 12: 68.7 -> 38.5 us):
// every MFMA operand lives in memory as [frag][lane(64)][elem(8)] so the
// consuming wave loads it as ONE coalesced 1KB instruction (16B/lane).
//   xpe/xv : frag_id = rowtile(256)*8 + ktile(8)
//   wfrag  : per mat, frag_id = n16(16)*8 + ktile
//   qfrag  : frag_id = head*256 + rowtile          (q pre-scaled by CL)
//   kfrag  : frag_id = (head*64 + keytile64)*4 + mt  (key-ID perm baked in)
//   vfrag  : frag_id = ((head*64+keytile64)*2+ks)*2+dh
// ===========================================================================

// ---------------------------------------------------------------------------
// prep: fragment-major bf16 conversion of x+pe, x, and the 4 weight mats.
// (frozen from round 12)
// ---------------------------------------------------------------------------
__global__ __launch_bounds__(256) void prep_kernel(
    const float* __restrict__ x, const float* __restrict__ pe,
    const int* __restrict__ xb,
    const float* __restrict__ Wq, const float* __restrict__ Wk,
    const float* __restrict__ Wv, const float* __restrict__ Wo,
    __bf16* __restrict__ xpef, __bf16* __restrict__ xvf,
    __bf16* __restrict__ wfrag, int* __restrict__ seg)
{
  const int bid  = blockIdx.x;
  const int wv4  = threadIdx.x >> 6;
  const int lane = threadIdx.x & 63;
  const int l15  = lane & 15, g = lane >> 4;

  if (bid < 512) {
    const int wid = bid * 4 + wv4;            // = rt*8 + kt
    const int rt = wid >> 3, kt = wid & 7;
    const float* xr = x  + (size_t)(rt * 16 + l15) * E + kt * 32 + 8 * g;
    const float* pr = pe + (size_t)(rt * 16 + l15) * E + kt * 32 + 8 * g;
    float4 a0 = *(const float4*)xr;
    float4 a1 = *(const float4*)(xr + 4);
    const float4 p0 = *(const float4*)pr;
    const float4 p1 = *(const float4*)(pr + 4);
    *reinterpret_cast<bf16x8*>(xvf + (size_t)wid * 512 + lane * 8) = pack8(a0, a1);
    a0.x += p0.x; a0.y += p0.y; a0.z += p0.z; a0.w += p0.w;
    a1.x += p1.x; a1.y += p1.y; a1.z += p1.z; a1.w += p1.w;
    *reinterpret_cast<bf16x8*>(xpef + (size_t)wid * 512 + lane * 8) = pack8(a0, a1);
  } else if (bid < 640) {
    const int wid = (bid - 512) * 4 + wv4;    // [0,512)
    const int mat = wid >> 7;
    const int rem = wid & 127;                // n16*8 + kt
    const int n16 = rem >> 3, kt = rem & 7;
    const float* __restrict__ W =
        (mat == 0) ? Wq : (mat == 1) ? Wk : (mat == 2) ? Wv : Wo;
    const float* wr = W + (size_t)(n16 * 16 + l15) * E + kt * 32 + 8 * g;
    *reinterpret_cast<bf16x8*>(wfrag + (size_t)wid * 512 + lane * 8) =
        pack8(*(const float4*)wr, *(const float4*)(wr + 4));
  } else {
    if (threadIdx.x <= BS) {
      const int t = threadIdx.x;
      int lo = 0, hi = N;
      while (lo < hi) { int mid = (lo + hi) >> 1; if (xb[mid] < t) lo = mid + 1; else hi = mid; }
      seg[t] = lo;
    }
  }
}

// ---------------------------------------------------------------------------
// MFMA QKV from fragment-major operands, A-reuse + W-window prefetch.
// (r14 structure; NEW r16: Q output pre-scaled by CL so the attention
// softmax needs no per-score multiply)
// ---------------------------------------------------------------------------
__global__ __launch_bounds__(256) void qkv_mfma(
    const __bf16* __restrict__ xpef, const __bf16* __restrict__ xvf,
    const __bf16* __restrict__ wfrag,
    const float* __restrict__ bq, const float* __restrict__ bk,
    const float* __restrict__ bv,
    __bf16* __restrict__ qfrag, __bf16* __restrict__ kfrag,
    __bf16* __restrict__ vfrag)
{
  const int mat  = blockIdx.y;
  const int rt   = blockIdx.x;
  const int wv   = threadIdx.x >> 6;
  const int lane = threadIdx.x & 63;
  const int l15  = lane & 15, g = lane >> 4;
  const int m0   = rt * 16;

  const __bf16* __restrict__ A = (mat < 2) ? xpef : xvf;
  const __bf16* __restrict__ W = wfrag + (size_t)mat * 65536;

  bf16x8 af[8];
#pragma unroll
  for (int kk = 0; kk < 8; ++kk)
    af[kk] = *reinterpret_cast<const bf16x8*>(A + (size_t)(rt * 8 + kk) * 512 + lane * 8);

  const int token = m0 + l15;
  const float oscale = (mat == 0) ? CL : 1.0f;   // fold softmax scale into Q

#pragma unroll
  for (int p = 0; p < 2; ++p) {
    const int cb0  = wv * 64 + p * 32;
    const int n16b = cb0 >> 4;
    const __bf16* __restrict__ Wp0 = W + (size_t)(n16b * 8) * 512 + lane * 8;
    const __bf16* __restrict__ Wp1 = W + (size_t)((n16b + 1) * 8) * 512 + lane * 8;

    f32x4 acc0 = {0.f, 0.f, 0.f, 0.f};
    f32x4 acc1 = {0.f, 0.f, 0.f, 0.f};

    bf16x8 ww[4];
    ww[0] = *reinterpret_cast<const bf16x8*>(Wp0);
    ww[1] = *reinterpret_cast<const bf16x8*>(Wp1);
    ww[2] = *reinterpret_cast<const bf16x8*>(Wp0 + 512);
    ww[3] = *reinterpret_cast<const bf16x8*>(Wp1 + 512);

#pragma unroll
    for (int kk = 0; kk < 8; ++kk) {
      const bf16x8 cw0 = ww[(2 * kk) & 3];
      const bf16x8 cw1 = ww[(2 * kk + 1) & 3];
      if (kk < 6) {
        ww[(2 * kk) & 3]     = *reinterpret_cast<const bf16x8*>(Wp0 + (size_t)(kk + 2) * 512);
        ww[(2 * kk + 1) & 3] = *reinterpret_cast<const bf16x8*>(Wp1 + (size_t)(kk + 2) * 512);
      }
      acc0 = __builtin_amdgcn_mfma_f32_16x16x32_bf16(cw0, af[kk], acc0, 0, 0, 0);
      acc1 = __builtin_amdgcn_mfma_f32_16x16x32_bf16(cw1, af[kk], acc1, 0, 0, 0);
    }

    const f32x4 accs[2] = {acc0, acc1};
    if (mat < 2) {
      const float* __restrict__ bi = mat ? bk : bq;
      __bf16* __restrict__ dst = mat ? kfrag : qfrag;
#pragma unroll
      for (int nt = 0; nt < 2; ++nt) {
        const int e  = cb0 + nt * 16 + 4 * g;   // 4 consecutive dims r=0..3
        const float4 bb = *(const float4*)(bi + e);
        const int h  = e >> 5;
        const int gp = (e & 31) >> 3;
        const int ib = e & 7;                   // 4*(g&1)
        bf16x4 o;
        o.x = (__bf16)((accs[nt][0] + bb.x) * oscale);
        o.y = (__bf16)((accs[nt][1] + bb.y) * oscale);
        o.z = (__bf16)((accs[nt][2] + bb.z) * oscale);
        o.w = (__bf16)((accs[nt][3] + bb.w) * oscale);
        size_t idx;
        if (mat == 0) {
          const int lp = (token & 15) + 16 * gp;
          idx = ((size_t)(h * 256 + rt) * 64 + lp) * 8 + ib;
        } else {
          const int t  = token >> 6, tk = token & 63;
          const int mt = 2 * (tk >> 5) + ((tk >> 2) & 1);
          const int lp = 4 * ((tk >> 3) & 3) + (tk & 3) + 16 * gp;
          idx = ((size_t)((h * 64 + t) * 4 + mt) * 64 + lp) * 8 + ib;
        }
        *reinterpret_cast<bf16x4*>(dst + idx) = o;
      }
    } else {
      const int t  = token >> 6, tk = token & 63;
      const int ks = (tk >> 5) & 1;
      const int gp = (tk >> 3) & 3;
      const int i  = tk & 7;
#pragma unroll
      for (int nt = 0; nt < 2; ++nt) {
        const int e0 = cb0 + nt * 16 + 4 * g;
        const float4 bb = *(const float4*)(bv + e0);
        const float bbr[4] = {bb.x, bb.y, bb.z, bb.w};
#pragma unroll
        for (int r = 0; r < 4; ++r) {
          const int d  = e0 + r;
          const int h  = d >> 5, dh = (d >> 4) & 1;
          const size_t idx =
              ((size_t)(((h * 64 + t) * 2 + ks) * 2 + dh) * 64 + (d & 15) + 16 * gp) * 8 + i;
          vfrag[idx] = (__bf16)(accs[nt][r] + bbr[r]);
        }
      }
    }
  }
}

// ---------------------------------------------------------------------------
// Fused attention + projection + residual + LayerNorm, fragment-major.
// (r14 structure; NEW r16:)
//  - XCD-chunked block mapping: rt = (bi&7)*32 + (bi>>3). Dispatch
//    round-robins blockIdx across the 8 XCDs, so this puts a segment's
//    32 contiguous row-tiles on ONE XCD -> per-XCD K/V working set ~0.5MB
//    (L2-resident) instead of streaming all 4MB from L3.
//  - interior-tile fast path: wave-uniform ballot picks a mask-free
//    softmax body when all 64 keys of the tile are inside every lane's
//    segment (~7 of 8 tiles); boundary tiles keep the masked body.
//  - no per-score CL multiply (folded into qfrag).
// ---------------------------------------------------------------------------
__global__ __launch_bounds__(512) void attn_proj_ln(
    const __bf16* __restrict__ qfrag, const __bf16* __restrict__ kfrag,
    const __bf16* __restrict__ vfrag, const int* __restrict__ xb,
    const int* __restrict__ seg,
    const float* __restrict__ x, const __bf16* __restrict__ wofrag,
    const float* __restrict__ bo, const float* __restrict__ gamma,
    const float* __restrict__ beta, float* __restrict__ out)
{
  const int bi   = blockIdx.x;
  const int rt   = (bi & 7) * 32 + (bi >> 3);   // XCD-chunked (256 = 8*32)
  const int m0   = rt * 16;
  const int h    = threadIdx.x >> 6;    // wave = head
  const int lane = threadIdx.x & 63;
  const int l15  = lane & 15;
  const int g    = lane >> 4;
  const int qrow = m0 + l15;

  __shared__ __bf16 cl[16][264];        // ctx tile, padded stride
  __shared__ float redS[8][16];
  __shared__ float redQ[8][16];

  // hoist phase-B Wo fragments (complete under phase A's compute)
  bf16x8 wreg[2][8];
#pragma unroll
  for (int nt = 0; nt < 2; ++nt)
#pragma unroll
    for (int kk = 0; kk < 8; ++kk)
      wreg[nt][kk] = *reinterpret_cast<const bf16x8*>(
          wofrag + (size_t)((h * 2 + nt) * 8 + kk) * 512 + lane * 8);

  // ======== phase A: attention ========
  {
    const int b  = xb[qrow];
    const int lo = seg[b];
    const int hi = seg[b + 1];

    const bf16x8 qf = *reinterpret_cast<const bf16x8*>(
        qfrag + (size_t)(h * 256 + rt) * 512 + lane * 8);

    const int kstart = __shfl(lo, 0, 64);
    const int kend   = __shfl(hi, 15, 64);

    f32x4 acc0 = {0.f, 0.f, 0.f, 0.f};
    f32x4 acc1 = {0.f, 0.f, 0.f, 0.f};
    float lsum = 0.f;

    for (int t = kstart >> 6; t * 64 < kend; ++t) {
      const int j0 = t * 64;
      const __bf16* kb4 = kfrag + (size_t)(h * 64 + t) * 2048 + lane * 8;
      const __bf16* vb4 = vfrag + (size_t)(h * 64 + t) * 2048 + lane * 8;

      const bf16x8 kf0 = *reinterpret_cast<const bf16x8*>(kb4);
      const bf16x8 kf1 = *reinterpret_cast<const bf16x8*>(kb4 + 512);
      const bf16x8 kf2 = *reinterpret_cast<const bf16x8*>(kb4 + 1024);
      const bf16x8 kf3 = *reinterpret_cast<const bf16x8*>(kb4 + 1536);
      const bf16x8 vf00 = *reinterpret_cast<const bf16x8*>(vb4);          // ks0,dh0
      const bf16x8 vf01 = *reinterpret_cast<const bf16x8*>(vb4 + 512);    // ks0,dh1
      const bf16x8 vf10 = *reinterpret_cast<const bf16x8*>(vb4 + 1024);   // ks1,dh0
      const bf16x8 vf11 = *reinterpret_cast<const bf16x8*>(vb4 + 1536);   // ks1,dh1

      const f32x4 z = {0.f, 0.f, 0.f, 0.f};
      f32x4 s[4];
      s[0] = __builtin_amdgcn_mfma_f32_16x16x32_bf16(kf0, qf, z, 0, 0, 0);
      s[1] = __builtin_amdgcn_mfma_f32_16x16x32_bf16(kf1, qf, z, 0, 0, 0);
      s[2] = __builtin_amdgcn_mfma_f32_16x16x32_bf16(kf2, qf, z, 0, 0, 0);
      s[3] = __builtin_amdgcn_mfma_f32_16x16x32_bf16(kf3, qf, z, 0, 0, 0);

      // wave-uniform interior test: all 64 keys inside every lane's segment
      const bool in_lane = (j0 >= lo) && (j0 + 64 <= hi);
      const bool interior =
          (__ballot(in_lane) == 0xFFFFFFFFFFFFFFFFull);

      bf16x8 pa[2];
      if (interior) {
#pragma unroll
        for (int ks = 0; ks < 2; ++ks)
#pragma unroll
          for (int b_ = 0; b_ < 2; ++b_)
#pragma unroll
            for (int r = 0; r < 4; ++r) {
              const float e = EXP2F(s[2 * ks + b_][r]);
              lsum += e;
              pa[ks][4 * b_ + r] = (__bf16)e;
            }
      } else {
#pragma unroll
        for (int ks = 0; ks < 2; ++ks)
#pragma unroll
          for (int b_ = 0; b_ < 2; ++b_)
#pragma unroll
            for (int r = 0; r < 4; ++r) {
              const int key = j0 + 32 * ks + 8 * g + 4 * b_ + r;
              const float e = (key >= lo && key < hi)
                                  ? EXP2F(s[2 * ks + b_][r]) : 0.f;
              lsum += e;
              pa[ks][4 * b_ + r] = (__bf16)e;
            }
      }

      acc0 = __builtin_amdgcn_mfma_f32_16x16x32_bf16(pa[0], vf00, acc0, 0, 0, 0);
      acc1 = __builtin_amdgcn_mfma_f32_16x16x32_bf16(pa[0], vf01, acc1, 0, 0, 0);
      acc0 = __builtin_amdgcn_mfma_f32_16x16x32_bf16(pa[1], vf10, acc0, 0, 0, 0);
      acc1 = __builtin_amdgcn_mfma_f32_16x16x32_bf16(pa[1], vf11, acc1, 0, 0, 0);
    }

    lsum += __shfl_xor(lsum, 16, 64);
    lsum += __shfl_xor(lsum, 32, 64);
    const float inv = 1.0f / lsum;
    float invr[4];
#pragma unroll
    for (int r = 0; r < 4; ++r) invr[r] = __shfl(inv, 4 * g + r, 64);

#pragma unroll
    for (int r = 0; r < 4; ++r) {
      cl[4 * g + r][h * DH + l15]      = (__bf16)(acc0[r] * invr[r]);
      cl[4 * g + r][h * DH + 16 + l15] = (__bf16)(acc1[r] * invr[r]);
    }
  }
  __syncthreads();

  // ======== phase B: projection + residual + LayerNorm ========
  {
    bf16x8 af[8];
#pragma unroll
    for (int kk = 0; kk < 8; ++kk)
      af[kk] = *reinterpret_cast<const bf16x8*>(&cl[l15][kk * 32 + 8 * g]);

    f32x4 acc[2];
    acc[0] = f32x4{0.f, 0.f, 0.f, 0.f};
    acc[1] = f32x4{0.f, 0.f, 0.f, 0.f};

#pragma unroll
    for (int kk = 0; kk < 8; ++kk)
#pragma unroll
      for (int nt = 0; nt < 2; ++nt)
        acc[nt] = __builtin_amdgcn_mfma_f32_16x16x32_bf16(af[kk], wreg[nt][kk],
                                                          acc[nt], 0, 0, 0);

    float yv[2][4];
    float s1[4], s2[4];
#pragma unroll
    for (int r = 0; r < 4; ++r) { s1[r] = 0.f; s2[r] = 0.f; }
#pragma unroll
    for (int nt = 0; nt < 2; ++nt) {
      const int c = h * 32 + nt * 16 + l15;
      const float bb = bo[c];
#pragma unroll
      for (int r = 0; r < 4; ++r) {
        const int row = m0 + 4 * g + r;
        const float y = acc[nt][r] + bb + x[(size_t)row * E + c];
        yv[nt][r] = y;
        s1[r] += y;
        s2[r] += y * y;
      }
    }
#pragma unroll
    for (int off = 1; off < 16; off <<= 1) {
#pragma unroll
      for (int r = 0; r < 4; ++r) {
        s1[r] += __shfl_xor(s1[r], off, 64);
        s2[r] += __shfl_xor(s2[r], off, 64);
      }
    }
    if (l15 == 0) {
#pragma unroll
      for (int r = 0; r < 4; ++r) {
        redS[h][4 * g + r] = s1[r];
        redQ[h][4 * g + r] = s2[r];
      }
    }
    __syncthreads();
    float mu[4], rs[4];
#pragma unroll
    for (int r = 0; r < 4; ++r) {
      float ts = 0.f, tq = 0.f;
#pragma unroll
      for (int w = 0; w < 8; ++w) { ts += redS[w][4 * g + r]; tq += redQ[w][4 * g + r]; }
      mu[r] = ts * (1.0f / E);
      const float var = tq * (1.0f / E) - mu[r] * mu[r];
      rs[r] = rsqrtf(var + 1e-5f);
    }
#pragma unroll
    for (int nt = 0; nt < 2; ++nt) {
      const int c = h * 32 + nt * 16 + l15;
      const float gg = gamma[c];
      const float bt = beta[c];
#pragma unroll
      for (int r = 0; r < 4; ++r) {
        const int row = m0 + 4 * g + r;
        out[(size_t)row * E + c] = (yv[nt][r] - mu[r]) * rs[r] * gg + bt;
      }
    }
  }
}

}  // namespace

extern "C" void kernel_launch(void* const* d_in, const int* in_sizes, int n_in,
                              void* d_out, int out_size, void* d_ws, size_t ws_size,
                              hipStream_t stream) {
  const float* x     = (const float*)d_in[0];
  const float* pe    = (const float*)d_in[1];
  const int*   xb    = (const int*)d_in[2];
  const float* Wq    = (const float*)d_in[3];
  const float* Wk    = (const float*)d_in[4];
  const float* Wv    = (const float*)d_in[5];
  const float* bq    = (const float*)d_in[6];
  const float* bk    = (const float*)d_in[7];
  const float* bv    = (const float*)d_in[8];
  const float* Wo    = (const float*)d_in[9];
  const float* bo    = (const float*)d_in[10];
  const float* gamma = (const float*)d_in[11];
  const float* beta  = (const float*)d_in[12];
  float* out = (float*)d_out;

  __bf16* ws = (__bf16*)d_ws;
  const size_t NE = (size_t)N * E;          // 1,048,576 elements
  __bf16* qfrag = ws;                       // 2 MB
  __bf16* kfrag = ws + NE;                  // 2 MB
  __bf16* vfrag = ws + 2 * NE;              // 2 MB
  __bf16* xpef  = ws + 3 * NE;              // 2 MB
  __bf16* xvf   = ws + 4 * NE;              // 2 MB
  __bf16* wfrag = ws + 5 * NE;              // 512 KB (4 mats x 65536)
  int*    seg   = (int*)(ws + 5 * NE + 4 * 65536);

  prep_kernel<<<dim3(641), 256, 0, stream>>>(x, pe, xb, Wq, Wk, Wv, Wo,
                                             xpef, xvf, wfrag, seg);
  qkv_mfma<<<dim3(256, 3), 256, 0, stream>>>(xpef, xvf, wfrag, bq, bk, bv,
                                             qfrag, kfrag, vfrag);
  attn_proj_ln<<<dim3(256), 512, 0, stream>>>(qfrag, kfrag, vfrag, xb, seg,
                                              x, wfrag + 3 * 65536,
                                              bo, gamma, beta, out);
}

// Round 17
// 37.546 us; speedup vs baseline: 1.1089x; 1.0798x over previous
//
#include <hip/hip_runtime.h>
#include <math.h>

namespace {

constexpr int N  = 4096;
constexpr int E  = 256;
constexpr int H  = 8;
constexpr int DH = 32;
constexpr int BS = 8;
// fold 1/sqrt(DH) and log2(e): softmax in exp2 domain, no max subtraction
// (f32-safe: |s*CL| realistic max ~16, overflow at 127 -> 27 sigma margin)
constexpr float CL = 0.17677669529663687f * 1.4426950408889634f;

typedef __bf16 bf16x8 __attribute__((ext_vector_type(8)));
typedef __bf16 bf16x4 __attribute__((ext_vector_type(4)));
typedef float  f32x4  __attribute__((ext_vector_type(4)));

#if __has_builtin(__builtin_amdgcn_exp2f)
#define EXP2F(x) __builtin_amdgcn_exp2f(x)
#else
#define EXP2F(x) __expf((x) * 0.6931471805599453f)
#endif

__device__ inline bf16x8 pack8(float4 a, float4 b) {
  bf16x8 r;
  r[0] = (__bf16)a.x; r[1] = (__bf16)a.y; r[2] = (__bf16)a.z; r[3] = (__bf16)a.w;
  r[4] = (__bf16)b.x; r[5] = (__bf16)b.y; r[6] = (__bf16)b.z; r[7] = (__bf16)b.w;
  return r;
}

// ===========================================================================
// FRAGMENT-MAJOR LAYOUTS (proven round 12: 68.7 -> 38.5 us):
// every MFMA operand lives in memory as [frag][lane(64)][elem(8)] so the
// consuming wave loads it as ONE coalesced 1KB instruction (16B/lane),
// instead of a 16-row x 512B-stride gather (~16 txns). frag element address
// is always  base + frag_id*512 + lane*8.
//   xpe/xv : frag_id = rowtile(256)*8 + ktile(8);   lane=(tok&15)+16g, k=32kt+8g+i
//   wfrag  : per mat, frag_id = n16(16)*8 + ktile;  lane=(n&15)+16g
//   qfrag  : frag_id = (head*256 + rowtile)         lane=(tok&15)+16g', e=32h+8g'+i
//   kfrag  : frag_id = (head*64 + keytile64)*4 + mt with the r5 key-ID
//            permutation baked in: slot m holds key 64t+8(m>>2)+(m&3)+32(mt>>1)+4(mt&1)
//   vfrag  : frag_id = ((head*64+keytile64)*2+ks)*2+dh; lane=(d&15)+16g',
//            elem i = key&7  (keys 64t+32ks+8g'+i)
// ===========================================================================

// ---------------------------------------------------------------------------
// prep: fragment-major bf16 conversion of x+pe, x, and the 4 weight mats.
//  blocks [0,512):   4 waves each: wave wid = rt*8+kt -> xpe_frag & xv_frag
//  blocks [512,640): wave wid -> one W fragment (mat = wid>>7)
//  block 640:        seg via binary search
// ---------------------------------------------------------------------------
__global__ __launch_bounds__(256) void prep_kernel(
    const float* __restrict__ x, const float* __restrict__ pe,
    const int* __restrict__ xb,
    const float* __restrict__ Wq, const float* __restrict__ Wk,
    const float* __restrict__ Wv, const float* __restrict__ Wo,
    __bf16* __restrict__ xpef, __bf16* __restrict__ xvf,
    __bf16* __restrict__ wfrag, int* __restrict__ seg)
{
  const int bid  = blockIdx.x;
  const int wv4  = threadIdx.x >> 6;
  const int lane = threadIdx.x & 63;
  const int l15  = lane & 15, g = lane >> 4;

  if (bid < 512) {
    const int wid = bid * 4 + wv4;            // = rt*8 + kt
    const int rt = wid >> 3, kt = wid & 7;
    const float* xr = x  + (size_t)(rt * 16 + l15) * E + kt * 32 + 8 * g;
    const float* pr = pe + (size_t)(rt * 16 + l15) * E + kt * 32 + 8 * g;
    float4 a0 = *(const float4*)xr;
    float4 a1 = *(const float4*)(xr + 4);
    const float4 p0 = *(const float4*)pr;
    const float4 p1 = *(const float4*)(pr + 4);
    *reinterpret_cast<bf16x8*>(xvf + (size_t)wid * 512 + lane * 8) = pack8(a0, a1);
    a0.x += p0.x; a0.y += p0.y; a0.z += p0.z; a0.w += p0.w;
    a1.x += p1.x; a1.y += p1.y; a1.z += p1.z; a1.w += p1.w;
    *reinterpret_cast<bf16x8*>(xpef + (size_t)wid * 512 + lane * 8) = pack8(a0, a1);
  } else if (bid < 640) {
    const int wid = (bid - 512) * 4 + wv4;    // [0,512)
    const int mat = wid >> 7;
    const int rem = wid & 127;                // n16*8 + kt
    const int n16 = rem >> 3, kt = rem & 7;
    const float* __restrict__ W =
        (mat == 0) ? Wq : (mat == 1) ? Wk : (mat == 2) ? Wv : Wo;
    const float* wr = W + (size_t)(n16 * 16 + l15) * E + kt * 32 + 8 * g;
    *reinterpret_cast<bf16x8*>(wfrag + (size_t)wid * 512 + lane * 8) =
        pack8(*(const float4*)wr, *(const float4*)(wr + 4));
  } else {
    if (threadIdx.x <= BS) {
      const int t = threadIdx.x;
      int lo = 0, hi = N;
      while (lo < hi) { int mid = (lo + hi) >> 1; if (xb[mid] < t) lo = mid + 1; else hi = mid; }
      seg[t] = lo;
    }
  }
}

// ---------------------------------------------------------------------------
// MFMA QKV from fragment-major operands: out = A @ W^T + b.
// Block = 16 rows x 128 cols, 4 waves (32-col slices), grid (512,3).
// All 24 loads per wave are coalesced 1KB frag loads; zero LDS, no barriers.
// Epilogue scatters acc (+bias) directly into q/k/vfrag layouts.
// ---------------------------------------------------------------------------
__global__ __launch_bounds__(256) void qkv_mfma(
    const __bf16* __restrict__ xpef, const __bf16* __restrict__ xvf,
    const __bf16* __restrict__ wfrag,
    const float* __restrict__ bq, const float* __restrict__ bk,
    const float* __restrict__ bv,
    __bf16* __restrict__ qfrag, __bf16* __restrict__ kfrag,
    __bf16* __restrict__ vfrag)
{
  const int mat  = blockIdx.y;
  const int rt   = blockIdx.x >> 1;
  const int half = blockIdx.x & 1;
  const int wv   = threadIdx.x >> 6;
  const int lane = threadIdx.x & 63;
  const int l15  = lane & 15, g = lane >> 4;
  const int m0   = rt * 16;
  const int cb0  = half * 128 + wv * 32;

  const __bf16* __restrict__ A = (mat < 2) ? xpef : xvf;
  const __bf16* __restrict__ W = wfrag + (size_t)mat * 65536;

  bf16x8 af[8];
#pragma unroll
  for (int kk = 0; kk < 8; ++kk)
    af[kk] = *reinterpret_cast<const bf16x8*>(A + (size_t)(rt * 8 + kk) * 512 + lane * 8);

  f32x4 acc0 = {0.f, 0.f, 0.f, 0.f};
  f32x4 acc1 = {0.f, 0.f, 0.f, 0.f};
  const int n16b = cb0 >> 4;
#pragma unroll
  for (int kk = 0; kk < 8; ++kk) {
    const bf16x8 wf0 = *reinterpret_cast<const bf16x8*>(
        W + (size_t)(n16b * 8 + kk) * 512 + lane * 8);
    const bf16x8 wf1 = *reinterpret_cast<const bf16x8*>(
        W + (size_t)((n16b + 1) * 8 + kk) * 512 + lane * 8);
    acc0 = __builtin_amdgcn_mfma_f32_16x16x32_bf16(wf0, af[kk], acc0, 0, 0, 0);
    acc1 = __builtin_amdgcn_mfma_f32_16x16x32_bf16(wf1, af[kk], acc1, 0, 0, 0);
  }

  const int token = m0 + l15;
  const f32x4 accs[2] = {acc0, acc1};

  if (mat < 2) {
    const float* __restrict__ bi = mat ? bk : bq;
    __bf16* __restrict__ dst = mat ? kfrag : qfrag;
#pragma unroll
    for (int nt = 0; nt < 2; ++nt) {
      const int e  = cb0 + nt * 16 + 4 * g;   // 4 consecutive dims r=0..3
      const float4 bb = *(const float4*)(bi + e);
      const int h  = e >> 5;
      const int gp = (e & 31) >> 3;
      const int ib = e & 7;                   // 4*(g&1)
      bf16x4 o;
      o.x = (__bf16)(accs[nt][0] + bb.x);
      o.y = (__bf16)(accs[nt][1] + bb.y);
      o.z = (__bf16)(accs[nt][2] + bb.z);
      o.w = (__bf16)(accs[nt][3] + bb.w);
      size_t idx;
      if (mat == 0) {
        const int lp = (token & 15) + 16 * gp;
        idx = ((size_t)(h * 256 + rt) * 64 + lp) * 8 + ib;
      } else {
        const int t  = token >> 6, tk = token & 63;
        const int mt = 2 * (tk >> 5) + ((tk >> 2) & 1);
        const int lp = 4 * ((tk >> 3) & 3) + (tk & 3) + 16 * gp;
        idx = ((size_t)((h * 64 + t) * 4 + mt) * 64 + lp) * 8 + ib;
      }
      *reinterpret_cast<bf16x4*>(dst + idx) = o;
    }
  } else {
    const int t  = token >> 6, tk = token & 63;
    const int ks = (tk >> 5) & 1;
    const int gp = (tk >> 3) & 3;
    const int i  = tk & 7;
#pragma unroll
    for (int nt = 0; nt < 2; ++nt) {
      const int e0 = cb0 + nt * 16 + 4 * g;
      const float4 bb = *(const float4*)(bv + e0);
      const float bbr[4] = {bb.x, bb.y, bb.z, bb.w};
#pragma unroll
      for (int r = 0; r < 4; ++r) {
        const int d  = e0 + r;
        const int h  = d >> 5, dh = (d >> 4) & 1;
        const size_t idx =
            ((size_t)(((h * 64 + t) * 2 + ks) * 2 + dh) * 64 + (d & 15) + 16 * gp) * 8 + i;
        vfrag[idx] = (__bf16)(accs[nt][r] + bbr[r]);
      }
    }
  }
}

// ---------------------------------------------------------------------------
// Fused attention + projection + residual + LayerNorm, fragment-major.
// Block = 16 query rows, 512 threads = 8 waves, wave = head.
// Phase A: free-running key loop (NO LDS staging, NO barriers, no vmcnt):
//   every kf/vf/qf load is one coalesced 1KB instruction from the frag
//   arrays; permuted key IDs are baked into kfrag so the S^T accumulator
//   regs are directly the P A-fragment slots; fixed-base exp2 softmax.
// Phase B: proven proj+LN, Wo read coalesced from wfrag[3].
// ---------------------------------------------------------------------------
__global__ __launch_bounds__(512) void attn_proj_ln(
    const __bf16* __restrict__ qfrag, const __bf16* __restrict__ kfrag,
    const __bf16* __restrict__ vfrag, const int* __restrict__ xb,
    const int* __restrict__ seg,
    const float* __restrict__ x, const __bf16* __restrict__ wofrag,
    const float* __restrict__ bo, const float* __restrict__ gamma,
    const float* __restrict__ beta, float* __restrict__ out)
{
  const int rt   = blockIdx.x;
  const int m0   = rt * 16;
  const int h    = threadIdx.x >> 6;    // wave = head
  const int lane = threadIdx.x & 63;
  const int l15  = lane & 15;
  const int g    = lane >> 4;
  const int qrow = m0 + l15;

  __shared__ __bf16 cl[16][264];        // ctx tile, padded stride
  __shared__ float redS[8][16];
  __shared__ float redQ[8][16];

  // ======== phase A: attention ========
  {
    const int b  = xb[qrow];
    const int lo = seg[b];
    const int hi = seg[b + 1];

    const bf16x8 qf = *reinterpret_cast<const bf16x8*>(
        qfrag + (size_t)(h * 256 + rt) * 512 + lane * 8);

    const int kstart = __shfl(lo, 0, 64);
    const int kend   = __shfl(hi, 15, 64);

    f32x4 acc0 = {0.f, 0.f, 0.f, 0.f};
    f32x4 acc1 = {0.f, 0.f, 0.f, 0.f};
    float lsum = 0.f;

    for (int t = kstart >> 6; t * 64 < kend; ++t) {
      const int j0 = t * 64;
      const __bf16* kb4 = kfrag + (size_t)(h * 64 + t) * 2048 + lane * 8;
      const __bf16* vb4 = vfrag + (size_t)(h * 64 + t) * 2048 + lane * 8;

      const bf16x8 kf0 = *reinterpret_cast<const bf16x8*>(kb4);
      const bf16x8 kf1 = *reinterpret_cast<const bf16x8*>(kb4 + 512);
      const bf16x8 kf2 = *reinterpret_cast<const bf16x8*>(kb4 + 1024);
      const bf16x8 kf3 = *reinterpret_cast<const bf16x8*>(kb4 + 1536);
      const bf16x8 vf00 = *reinterpret_cast<const bf16x8*>(vb4);          // ks0,dh0
      const bf16x8 vf01 = *reinterpret_cast<const bf16x8*>(vb4 + 512);    // ks0,dh1
      const bf16x8 vf10 = *reinterpret_cast<const bf16x8*>(vb4 + 1024);   // ks1,dh0
      const bf16x8 vf11 = *reinterpret_cast<const bf16x8*>(vb4 + 1536);   // ks1,dh1

      const f32x4 z = {0.f, 0.f, 0.f, 0.f};
      f32x4 s[4];
      s[0] = __builtin_amdgcn_mfma_f32_16x16x32_bf16(kf0, qf, z, 0, 0, 0);
      s[1] = __builtin_amdgcn_mfma_f32_16x16x32_bf16(kf1, qf, z, 0, 0, 0);
      s[2] = __builtin_amdgcn_mfma_f32_16x16x32_bf16(kf2, qf, z, 0, 0, 0);
      s[3] = __builtin_amdgcn_mfma_f32_16x16x32_bf16(kf3, qf, z, 0, 0, 0);

      bf16x8 pa[2];
#pragma unroll
      for (int ks = 0; ks < 2; ++ks)
#pragma unroll
        for (int b_ = 0; b_ < 2; ++b_)
#pragma unroll
          for (int r = 0; r < 4; ++r) {
            const int key = j0 + 32 * ks + 8 * g + 4 * b_ + r;
            const float sc = s[2 * ks + b_][r] * CL;
            const float e  = (key >= lo && key < hi) ? EXP2F(sc) : 0.f;
            lsum += e;
            pa[ks][4 * b_ + r] = (__bf16)e;
          }

      acc0 = __builtin_amdgcn_mfma_f32_16x16x32_bf16(pa[0], vf00, acc0, 0, 0, 0);
      acc1 = __builtin_amdgcn_mfma_f32_16x16x32_bf16(pa[0], vf01, acc1, 0, 0, 0);
      acc0 = __builtin_amdgcn_mfma_f32_16x16x32_bf16(pa[1], vf10, acc0, 0, 0, 0);
      acc1 = __builtin_amdgcn_mfma_f32_16x16x32_bf16(pa[1], vf11, acc1, 0, 0, 0);
    }

    lsum += __shfl_xor(lsum, 16, 64);
    lsum += __shfl_xor(lsum, 32, 64);
    const float inv = 1.0f / lsum;
    float invr[4];
#pragma unroll
    for (int r = 0; r < 4; ++r) invr[r] = __shfl(inv, 4 * g + r, 64);

#pragma unroll
    for (int r = 0; r < 4; ++r) {
      cl[4 * g + r][h * DH + l15]      = (__bf16)(acc0[r] * invr[r]);
      cl[4 * g + r][h * DH + 16 + l15] = (__bf16)(acc1[r] * invr[r]);
    }
  }
  __syncthreads();

  // ======== phase B: projection + residual + LayerNorm ========
  {
    bf16x8 af[8];
#pragma unroll
    for (int kk = 0; kk < 8; ++kk)
      af[kk] = *reinterpret_cast<const bf16x8*>(&cl[l15][kk * 32 + 8 * g]);

    f32x4 acc[2];
    acc[0] = f32x4{0.f, 0.f, 0.f, 0.f};
    acc[1] = f32x4{0.f, 0.f, 0.f, 0.f};

#pragma unroll
    for (int kk = 0; kk < 8; ++kk)
#pragma unroll
      for (int nt = 0; nt < 2; ++nt) {
        const bf16x8 wf = *reinterpret_cast<const bf16x8*>(
            wofrag + (size_t)((h * 2 + nt) * 8 + kk) * 512 + lane * 8);
        acc[nt] = __builtin_amdgcn_mfma_f32_16x16x32_bf16(af[kk], wf, acc[nt], 0, 0, 0);
      }

    float yv[2][4];
    float s1[4], s2[4];
#pragma unroll
    for (int r = 0; r < 4; ++r) { s1[r] = 0.f; s2[r] = 0.f; }
#pragma unroll
    for (int nt = 0; nt < 2; ++nt) {
      const int c = h * 32 + nt * 16 + l15;
      const float bb = bo[c];
#pragma unroll
      for (int r = 0; r < 4; ++r) {
        const int row = m0 + 4 * g + r;
        const float y = acc[nt][r] + bb + x[(size_t)row * E + c];
        yv[nt][r] = y;
        s1[r] += y;
        s2[r] += y * y;
      }
    }
#pragma unroll
    for (int off = 1; off < 16; off <<= 1) {
#pragma unroll
      for (int r = 0; r < 4; ++r) {
        s1[r] += __shfl_xor(s1[r], off, 64);
        s2[r] += __shfl_xor(s2[r], off, 64);
      }
    }
    if (l15 == 0) {
#pragma unroll
      for (int r = 0; r < 4; ++r) {
        redS[h][4 * g + r] = s1[r];
        redQ[h][4 * g + r] = s2[r];
      }
    }
    __syncthreads();
    float mu[4], rs[4];
#pragma unroll
    for (int r = 0; r < 4; ++r) {
      float ts = 0.f, tq = 0.f;
#pragma unroll
      for (int w = 0; w < 8; ++w) { ts += redS[w][4 * g + r]; tq += redQ[w][4 * g + r]; }
      mu[r] = ts * (1.0f / E);
      const float var = tq * (1.0f / E) - mu[r] * mu[r];
      rs[r] = rsqrtf(var + 1e-5f);
    }
#pragma unroll
    for (int nt = 0; nt < 2; ++nt) {
      const int c = h * 32 + nt * 16 + l15;
      const float gg = gamma[c];
      const float bt = beta[c];
#pragma unroll
      for (int r = 0; r < 4; ++r) {
        const int row = m0 + 4 * g + r;
        out[(size_t)row * E + c] = (yv[nt][r] - mu[r]) * rs[r] * gg + bt;
      }
    }
  }
}

}  // namespace

extern "C" void kernel_launch(void* const* d_in, const int* in_sizes, int n_in,
                              void* d_out, int out_size, void* d_ws, size_t ws_size,
                              hipStream_t stream) {
  const float* x     = (const float*)d_in[0];
  const float* pe    = (const float*)d_in[1];
  const int*   xb    = (const int*)d_in[2];
  const float* Wq    = (const float*)d_in[3];
  const float* Wk    = (const float*)d_in[4];
  const float* Wv    = (const float*)d_in[5];
  const float* bq    = (const float*)d_in[6];
  const float* bk    = (const float*)d_in[7];
  const float* bv    = (const float*)d_in[8];
  const float* Wo    = (const float*)d_in[9];
  const float* bo    = (const float*)d_in[10];
  const float* gamma = (const float*)d_in[11];
  const float* beta  = (const float*)d_in[12];
  float* out = (float*)d_out;

  __bf16* ws = (__bf16*)d_ws;
  const size_t NE = (size_t)N * E;          // 1,048,576 elements
  __bf16* qfrag = ws;                       // 2 MB
  __bf16* kfrag = ws + NE;                  // 2 MB
  __bf16* vfrag = ws + 2 * NE;              // 2 MB
  __bf16* xpef  = ws + 3 * NE;              // 2 MB
  __bf16* xvf   = ws + 4 * NE;              // 2 MB
  __bf16* wfrag = ws + 5 * NE;              // 512 KB (4 mats x 65536)
  int*    seg   = (int*)(ws + 5 * NE + 4 * 65536);

  prep_kernel<<<dim3(641), 256, 0, stream>>>(x, pe, xb, Wq, Wk, Wv, Wo,
                                             xpef, xvf, wfrag, seg);
  qkv_mfma<<<dim3(512, 3), 256, 0, stream>>>(xpef, xvf, wfrag, bq, bk, bv,
                                             qfrag, kfrag, vfrag);
  attn_proj_ln<<<dim3(256), 512, 0, stream>>>(qfrag, kfrag, vfrag, xb, seg,
                                              x, wfrag + 3 * 65536,
                                              bo, gamma, beta, out);
}